// Round 14
// baseline (2903.283 us; speedup 1.0000x reference)
//
#include <hip/hip_runtime.h>

typedef _Float16 f16;
typedef _Float16 f16x4 __attribute__((ext_vector_type(4)));
typedef _Float16 f16x8 __attribute__((ext_vector_type(8)));
typedef float f32x4 __attribute__((ext_vector_type(4)));

#define B_ 4096
#define N_ 32768
#define D_ 1024
#define BM 64
#define BN 128
#define THREADS 1024          // 16 waves, 1 block/CU, 4 waves/SIMD
#define NSPL 4                // N-split for both passes
#define LN256 5.545177444479562f

__device__ __forceinline__ f32x4 mfma16(f16x8 a, f16x8 b, f32x4 c) {
    return __builtin_amdgcn_mfma_f32_16x16x32_f16(a, b, c, 0, 0, 0);
}

// ---- K -> fragment-order f16 --------------------------------------------------
// Group (rb, ks): 16 K-rows x 32 k-cols; lane (lg*16+l15) holds
// K[rb*16+l15][ks*32+lg*8 .. +8].  Kf[((rb*32+ks)*64+lane)*8]
__global__ void conv_kf(const float* __restrict__ K, f16* __restrict__ Kf) {
    int tid = blockIdx.x * 256 + threadIdx.x;       // < N_*D_/8
    int g = tid >> 6, lane = tid & 63;
    int rb = g >> 5, ks = g & 31;
    int l15 = lane & 15, lg = lane >> 4;
    const float* s = K + (size_t)(rb * 16 + l15) * D_ + ks * 32 + lg * 8;
    float4 a = *(const float4*)s, b = *(const float4*)(s + 4);
    f16x8 h;
    h[0] = (f16)a.x; h[1] = (f16)a.y; h[2] = (f16)a.z; h[3] = (f16)a.w;
    h[4] = (f16)b.x; h[5] = (f16)b.y; h[6] = (f16)b.z; h[7] = (f16)b.w;
    *(f16x8*)(Kf + (size_t)tid * 8) = h;
}

// ---- V -> fragment-order f16 (PV B-operand) -----------------------------------
// Group (kb, db): 32 kv-rows x 16 d-cols; lane holds V[kb*32+lg*8+j][db*16+l15].
// Vf[((kb*64+db)*64+lane)*8]
__global__ void conv_vf(const float* __restrict__ V, f16* __restrict__ Vf) {
    int tid = blockIdx.x * 256 + threadIdx.x;       // < N_*D_/8
    int g = tid >> 6, lane = tid & 63;
    int db = g & 63, kb = g >> 6;
    int l15 = lane & 15, lg = lane >> 4;
    const float* s = V + (size_t)(kb * 32 + lg * 8) * D_ + db * 16 + l15;
    f16x8 h;
    #pragma unroll
    for (int j = 0; j < 8; ++j) h[j] = (f16)s[(size_t)j * D_];
    *(f16x8*)(Vf + (size_t)tid * 8) = h;
}

// ---- X: fp32 [B][D] -> f16, k-major per 64-row tile ---------------------------
// elem(bblk,row,d) -> Xp[bblk*65536 + (d>>5)*2048 + row*32 + ((d&31)>>3)*8 + (d&7)]
__global__ void conv_xp(const float* __restrict__ X, f16* __restrict__ Xp) {
    int idx = blockIdx.x * 256 + threadIdx.x;       // < B*D/8
    int b  = idx >> 7;
    int d0 = (idx & 127) << 3;
    const float* s = X + (size_t)b * D_ + d0;
    float4 a = *(const float4*)s, c = *(const float4*)(s + 4);
    f16x8 h;
    h[0] = (f16)a.x; h[1] = (f16)a.y; h[2] = (f16)a.z; h[3] = (f16)a.w;
    h[4] = (f16)c.x; h[5] = (f16)c.y; h[6] = (f16)c.z; h[7] = (f16)c.w;
    int bblk = b >> 6, row = b & 63, dblk = d0 >> 5, sub = (d0 & 31) >> 3;
    *(f16x8*)(Xp + (size_t)bblk * (BM * D_) + dblk * 2048 + row * 32 + sub * 8) = h;
}

// ---- PASS 1: per-row (max, sumexp) over each N-chunk --------------------------
// 16 waves: wave (rg=w&3, cs=w>>2): 16 rows x 32 cols per tile; per-lane running
// (m,l); barrier-free main loop; lane/LDS merge at the end.
__global__ __launch_bounds__(THREADS, 1)
void attn_pass1(const f16* __restrict__ Xp, const f16* __restrict__ Kf,
                float* __restrict__ Mp, float* __restrict__ Lp)
{
    __shared__ __align__(16) f16 Xh[BM * D_];    // 128 KB, k-major
    __shared__ float2 red[BM][5];

    const int NCHUNK = N_ / NSPL;                // 8192
    const int ITERS  = NCHUNK / BN;              // 64
    const int bid = blockIdx.x;
    const int chunk = (bid & 7) >> 1;            // chunk -> XCD pair
    const int bblk  = ((bid >> 3) << 1) | (bid & 1);
    const int b0 = bblk * BM;
    const int t  = threadIdx.x;

    {
        const f16* xsrc = Xp + (size_t)bblk * (BM * D_);
        for (int c = t; c < BM * D_ / 8; c += THREADS)
            *(f16x8*)((char*)Xh + c * 16) = *(const f16x8*)(xsrc + c * 8);
    }
    __syncthreads();

    const int wave = t >> 6, lane = t & 63;
    const int l15 = lane & 15, lg = lane >> 4;
    const int rg = wave & 3, cs = wave >> 2;

    const char* bha = (const char*)Xh + rg * 1024 + l15 * 64 + lg * 16;
    // fragment pointers: rb0 = chunk-base rb + strip's two row-blocks
    const int rb0 = (chunk * NCHUNK) / 16;
    const f16* kp0 = Kf + ((size_t)(rb0 + cs * 2) * 32 * 64 + lane) * 8;
    const f16* kp1 = kp0 + 16384;                // next rb: 32*64*8 f16

    float m[4], l[4];
    #pragma unroll
    for (int i = 0; i < 4; ++i) { m[i] = -INFINITY; l[i] = 0.f; }

    for (int it = 0; it < ITERS; ++it) {
        f32x4 S0 = (f32x4){0.f, 0.f, 0.f, 0.f};
        f32x4 S1 = (f32x4){0.f, 0.f, 0.f, 0.f};
        #pragma unroll
        for (int ks = 0; ks < 32; ++ks) {
            f16x8 k0 = *(const f16x8*)(kp0 + ks * 512);
            f16x8 k1 = *(const f16x8*)(kp1 + ks * 512);
            f16x8 ah = *(const f16x8*)(bha + ks * 4096);
            S0 = mfma16(ah, k0, S0);
            S1 = mfma16(ah, k1, S1);
        }
        #pragma unroll
        for (int i = 0; i < 4; ++i) {
            float a = S0[i], b = S1[i];
            float mn = fmaxf(m[i], fmaxf(a, b));
            l[i] = l[i] * __expf(m[i] - mn) + __expf(a - mn) + __expf(b - mn);
            m[i] = mn;
        }
        kp0 += (size_t)8 * 16384;                // advance BN/16 = 8 rbs
        kp1 += (size_t)8 * 16384;
    }

    // merge across the 16 col-lanes sharing the same rows
    #pragma unroll
    for (int i = 0; i < 4; ++i) {
        #pragma unroll
        for (int d = 1; d < 16; d <<= 1) {
            float m2 = __shfl_xor(m[i], d);
            float l2 = __shfl_xor(l[i], d);
            float mn = fmaxf(m[i], m2);
            l[i] = l[i] * __expf(m[i] - mn) + l2 * __expf(m2 - mn);
            m[i] = mn;
        }
    }
    if (l15 == 0) {
        #pragma unroll
        for (int i = 0; i < 4; ++i)
            red[rg * 16 + lg * 4 + i][cs] = make_float2(m[i], l[i]);
    }
    __syncthreads();

    if (t < BM) {
        float2 r0 = red[t][0];
        float M = r0.x, L = r0.y;
        #pragma unroll
        for (int s2 = 1; s2 < 4; ++s2) {
            float2 r2 = red[t][s2];
            float mn = fmaxf(M, r2.x);
            L = L * __expf(M - mn) + r2.y * __expf(r2.x - mn);
            M = mn;
        }
        Mp[(size_t)chunk * B_ + b0 + t] = M;
        Lp[(size_t)chunk * B_ + b0 + t] = L;
    }
}

// ---- combine pass-1 partials: C[b] = M + ln(L) - ln(256) ----------------------
__global__ void combine1(const float* __restrict__ Mp, const float* __restrict__ Lp,
                         float* __restrict__ Cp)
{
    int b = blockIdx.x * 256 + threadIdx.x;
    float M = -INFINITY;
    #pragma unroll
    for (int c = 0; c < NSPL; ++c) M = fmaxf(M, Mp[(size_t)c * B_ + b]);
    float L = 0.f;
    #pragma unroll
    for (int c = 0; c < NSPL; ++c)
        L += Lp[(size_t)c * B_ + b] * __expf(Mp[(size_t)c * B_ + b] - M);
    Cp[b] = M + __logf(L) - LN256;
}

// ---- PASS 2: O = sum P*V with P = exp(S - C) in (0,256] -----------------------
// Same QK wave layout; PV: wave owns 64 D-cols (4 fn). No softmax state:
// accs = O(64)+S(8); arch ~55 -> fits the 128/lane cap at 4 waves/SIMD.
__global__ __launch_bounds__(THREADS, 1)
void attn_pass2(const f16* __restrict__ Xp, const f16* __restrict__ Kf,
                const f16* __restrict__ Vf, const float* __restrict__ Cp,
                f16* __restrict__ Oph)
{
    __shared__ __align__(16) f16 Xh[BM * D_];    // 128 KB, k-major
    __shared__ __align__(16) f16 Pl[BM * BN];    // 16 KB, k-major

    const int NCHUNK = N_ / NSPL;                // 8192
    const int ITERS  = NCHUNK / BN;              // 64
    const int bid = blockIdx.x;
    const int chunk = (bid & 7) >> 1;
    const int bblk  = ((bid >> 3) << 1) | (bid & 1);
    const int b0 = bblk * BM;
    const int t  = threadIdx.x;

    {
        const f16* xsrc = Xp + (size_t)bblk * (BM * D_);
        for (int c = t; c < BM * D_ / 8; c += THREADS)
            *(f16x8*)((char*)Xh + c * 16) = *(const f16x8*)(xsrc + c * 8);
    }
    __syncthreads();

    const int wave = t >> 6, lane = t & 63;
    const int l15 = lane & 15, lg = lane >> 4;
    const int rg = wave & 3, cs = wave >> 2;

    const char* bha = (const char*)Xh + rg * 1024 + l15 * 64 + lg * 16;
    const char* prb = (const char*)Pl + l15 * 64 + lg * 16;

    const int rb0 = (chunk * NCHUNK) / 16;
    const f16* kp0 = Kf + ((size_t)(rb0 + cs * 2) * 32 * 64 + lane) * 8;
    const f16* kp1 = kp0 + 16384;
    // V: kb0 = chunk base / 32; wave owns db = wave*4 .. +3
    const f16* vbase = Vf + (((size_t)((chunk * NCHUNK) / 32) * 64 + wave * 4) * 64 + lane) * 8;

    float Cq[4];
    #pragma unroll
    for (int i = 0; i < 4; ++i)
        Cq[i] = Cp[b0 + rg * 16 + lg * 4 + i];

    f32x4 S0, S1;
    auto QK = [&]() {
        S0 = (f32x4){0.f, 0.f, 0.f, 0.f};
        S1 = (f32x4){0.f, 0.f, 0.f, 0.f};
        #pragma unroll
        for (int ks = 0; ks < 32; ++ks) {
            f16x8 k0 = *(const f16x8*)(kp0 + ks * 512);
            f16x8 k1 = *(const f16x8*)(kp1 + ks * 512);
            f16x8 ah = *(const f16x8*)(bha + ks * 4096);
            S0 = mfma16(ah, k0, S0);
            S1 = mfma16(ah, k1, S1);
        }
    };

    f32x4 O[4][4];
    #pragma unroll
    for (int rg2 = 0; rg2 < 4; ++rg2)
        #pragma unroll
        for (int fn = 0; fn < 4; ++fn) O[rg2][fn] = (f32x4){0.f, 0.f, 0.f, 0.f};

    QK();   // tile 0

    for (int it = 0; it < ITERS; ++it) {
        // ---- P = exp(S - C'), final values, straight to LDS ----
        #pragma unroll
        for (int i = 0; i < 4; ++i) {
            float p0 = __expf(S0[i] - Cq[i]);
            float p1 = __expf(S1[i] - Cq[i]);
            int mrow = rg * 16 + lg * 4 + i;
            int off0 = cs * 4096 + mrow * 64 + ((l15 >> 3) << 4) + ((l15 & 7) << 1);
            *(f16*)((char*)Pl + off0)      = (f16)p0;
            *(f16*)((char*)Pl + off0 + 32) = (f16)p1;
        }
        __syncthreads();

        // ---- PV: O += P x V (fragment-order V, contiguous 1KB wave loads) ----
        #pragma unroll
        for (int ks2 = 0; ks2 < 4; ++ks2) {
            f16x8 pa[4];
            #pragma unroll
            for (int rg2 = 0; rg2 < 4; ++rg2)
                pa[rg2] = *(const f16x8*)(prb + rg2 * 1024 + ks2 * 4096);
            #pragma unroll
            for (int fn = 0; fn < 4; ++fn) {
                f16x8 vv = *(const f16x8*)(vbase + ks2 * 32768 + fn * 512);
                #pragma unroll
                for (int rg2 = 0; rg2 < 4; ++rg2)
                    O[rg2][fn] = mfma16(pa[rg2], vv, O[rg2][fn]);
            }
        }

        // ---- advance; next tile's QK before the closing barrier ----
        kp0 += (size_t)8 * 16384;
        kp1 += (size_t)8 * 16384;
        vbase += (size_t)4 * 32768;
        if (it + 1 < ITERS) QK();
        __syncthreads();
    }

    // ---- epilogue: f16 partial O (256-scaled; fixed in combine2) ----
    f16* Op = Oph + (size_t)chunk * B_ * D_;
    #pragma unroll
    for (int rg2 = 0; rg2 < 4; ++rg2)
        #pragma unroll
        for (int fn = 0; fn < 4; ++fn)
            #pragma unroll
            for (int i = 0; i < 4; ++i) {
                int col = wave * 64 + fn * 16 + l15;
                int row = b0 + rg2 * 16 + lg * 4 + i;
                Op[(size_t)row * D_ + col] = (f16)O[rg2][fn][i];
            }
}

// ---- combine pass-2 partials: Out = (sum_chunks Oph) / 256 --------------------
__global__ void combine2(const f16* __restrict__ Oph, float* __restrict__ Outg) {
    int row = blockIdx.x;
    int i = threadIdx.x;
    size_t base = (size_t)row * D_ + i * 4;
    float4 r = make_float4(0.f, 0.f, 0.f, 0.f);
    #pragma unroll
    for (int c = 0; c < NSPL; ++c) {
        f16x4 a = *(const f16x4*)(Oph + (size_t)c * B_ * D_ + base);
        r.x += (float)a[0]; r.y += (float)a[1];
        r.z += (float)a[2]; r.w += (float)a[3];
    }
    const float s = 1.f / 256.f;
    r.x *= s; r.y *= s; r.z *= s; r.w *= s;
    *(float4*)(Outg + base) = r;
}

extern "C" void kernel_launch(void* const* d_in, const int* in_sizes, int n_in,
                              void* d_out, int out_size, void* d_ws, size_t ws_size,
                              hipStream_t stream) {
    const float* X = (const float*)d_in[0];
    const float* K = (const float*)d_in[1];
    const float* V = (const float*)d_in[2];
    float* Out = (float*)d_out;

    const size_t szKf = (size_t)N_ * D_ * sizeof(f16);       // 64 MiB
    const size_t szVf = (size_t)N_ * D_ * sizeof(f16);       // 64 MiB
    const size_t szXp = (size_t)B_ * D_ * sizeof(f16);       // 8 MiB
    const size_t szOp = (size_t)NSPL * B_ * D_ * sizeof(f16);// 32 MiB
    const size_t szM  = (size_t)NSPL * B_ * sizeof(float);   // 64 KiB

    f16*   Kf = (f16*)d_ws;
    f16*   Vf = (f16*)((char*)d_ws + szKf);
    f16*   Xp = (f16*)((char*)d_ws + szKf + szVf);
    f16*   Oph = (f16*)((char*)d_ws + szKf + szVf + szXp);
    float* Mp = (float*)((char*)Oph + szOp);
    float* Lp = (float*)((char*)Mp + szM);
    float* Cpv = (float*)((char*)Lp + szM);

    conv_kf<<<(N_ * D_ / 8) / 256, 256, 0, stream>>>(K, Kf);
    conv_vf<<<(N_ * D_ / 8) / 256, 256, 0, stream>>>(V, Vf);
    conv_xp<<<(B_ * D_ / 8) / 256, 256, 0, stream>>>(X, Xp);

    attn_pass1<<<(B_ / BM) * NSPL, THREADS, 0, stream>>>(Xp, Kf, Mp, Lp);
    combine1<<<B_ / 256, 256, 0, stream>>>(Mp, Lp, Cpv);
    attn_pass2<<<(B_ / BM) * NSPL, THREADS, 0, stream>>>(Xp, Kf, Vf, Cpv, Oph);
    combine2<<<B_, 256, 0, stream>>>(Oph, Out);
}

// Round 15
// 873.039 us; speedup vs baseline: 3.3255x; 3.3255x over previous
//
#include <hip/hip_runtime.h>

typedef _Float16 f16;
typedef _Float16 f16x8 __attribute__((ext_vector_type(8)));
typedef float f32x4 __attribute__((ext_vector_type(4)));

#define B_ 4096
#define N_ 32768
#define D_ 1024
#define BM 32
#define BN 256          // KV tile per iteration (32 cols per wave x 8 waves)
#define THREADS 512
#define DSLICE 128      // D columns owned per wave in PV
#define NHALF (N_ / 2)
#define ITERS (NHALF / BN)   // 64

__device__ __forceinline__ f32x4 mfma16(f16x8 a, f16x8 b, f32x4 c) {
    return __builtin_amdgcn_mfma_f32_16x16x32_f16(a, b, c, 0, 0, 0);
}

// ---- K -> fragment-order f16 --------------------------------------------------
// Group (rb, ks): 16 K-rows x 32 k-cols; lane (lg*16+l15) holds
// K[rb*16+l15][ks*32+lg*8 .. +8].  Kf[((rb*32+ks)*64+lane)*8]
// -> hot-loop load = base + lane*16B: one contiguous 1KB wave-load.
__global__ void conv_kf(const float* __restrict__ K, f16* __restrict__ Kf) {
    int tid = blockIdx.x * 256 + threadIdx.x;       // < N_*D_/8
    int g = tid >> 6, lane = tid & 63;
    int rb = g >> 5, ks = g & 31;
    int l15 = lane & 15, lg = lane >> 4;
    const float* s = K + (size_t)(rb * 16 + l15) * D_ + ks * 32 + lg * 8;
    float4 a = *(const float4*)s, b = *(const float4*)(s + 4);
    f16x8 h;
    h[0] = (f16)a.x; h[1] = (f16)a.y; h[2] = (f16)a.z; h[3] = (f16)a.w;
    h[4] = (f16)b.x; h[5] = (f16)b.y; h[6] = (f16)b.z; h[7] = (f16)b.w;
    *(f16x8*)(Kf + (size_t)tid * 8) = h;
}

// ---- V -> fragment-order f16 (PV B-operand) -----------------------------------
// Group (kb, db): 32 kv-rows x 16 d-cols; lane holds V[kb*32+lg*8+j][db*16+l15].
// Vf[((kb*64+db)*64+lane)*8]
__global__ void conv_vf(const float* __restrict__ V, f16* __restrict__ Vf) {
    int tid = blockIdx.x * 256 + threadIdx.x;       // < N_*D_/8
    int g = tid >> 6, lane = tid & 63;
    int db = g & 63, kb = g >> 6;
    int l15 = lane & 15, lg = lane >> 4;
    const float* s = V + (size_t)(kb * 32 + lg * 8) * D_ + db * 16 + l15;
    f16x8 h;
    #pragma unroll
    for (int j = 0; j < 8; ++j) h[j] = (f16)s[(size_t)j * D_];
    *(f16x8*)(Vf + (size_t)tid * 8) = h;
}

// ---- main fused attention kernel ----------------------------------------------
// k-major LDS for X/P: off(row,d) = (d>>5)*2048 + row*64 + ((d&31)>>3)*16 + (d&7)*2
// All global K/V loads are lane-contiguous 1KB wave-loads (fragment order).
// SINGLE barrier per iteration via 2-deep Pl/red double-buffer: barrier-release
// arithmetic bounds wave skew to one loop body, so write(pb^1) never races
// read(pb).  Defer-max: skip alpha/exp/O-rescale when no row max increased.
__global__ __launch_bounds__(THREADS, 2)
void attn_main(const float* __restrict__ Xg, const f16* __restrict__ Kf,
               const f16* __restrict__ Vf, float* __restrict__ Opart,
               float* __restrict__ Mpart, float* __restrict__ Lpart)
{
    __shared__ __align__(16) f16 Xh[BM * D_];     // 64 KB, k-major
    __shared__ __align__(16) f16 Pl[2][BM * BN];  // 2 x 16 KB, k-major
    __shared__ float2 red[2][BM][9];              // 2 x 2.3 KB, padded

    const int xcd   = blockIdx.x & 7;
    const int chunk = xcd >> 2;
    const int bblk  = ((blockIdx.x >> 3) << 2) | (xcd & 3);
    const int kvbase = chunk * NHALF;
    const int b0 = bblk * BM;
    const int t  = threadIdx.x;

    // --- stage X: fp32 -> f16 into k-major LDS ---
    for (int c = t; c < BM * D_ / 8; c += THREADS) {
        int dblk = c >> 7;
        int row  = (c >> 2) & 31;
        int sub  = c & 3;
        int d0   = dblk * 32 + sub * 8;
        const float* s = Xg + (size_t)(b0 + row) * D_ + d0;
        float4 a = *(const float4*)s, b = *(const float4*)(s + 4);
        f16x8 hi;
        hi[0] = (f16)a.x; hi[1] = (f16)a.y; hi[2] = (f16)a.z; hi[3] = (f16)a.w;
        hi[4] = (f16)b.x; hi[5] = (f16)b.y; hi[6] = (f16)b.z; hi[7] = (f16)b.w;
        *(f16x8*)((char*)Xh + dblk * 2048 + row * 64 + sub * 16) = hi;
    }
    __syncthreads();

    const int wave = t >> 6, lane = t & 63;
    const int l15 = lane & 15, lg = lane >> 4;

    const char* bh0 = (const char*)Xh + l15 * 64 + lg * 16;
    const char* bh1 = (const char*)Xh + (l15 + 16) * 64 + lg * 16;
    const char* pr0 = (const char*)&Pl[0][0] + l15 * 64 + lg * 16;
    const char* pr1 = (const char*)&Pl[0][0] + (l15 + 16) * 64 + lg * 16;

    // K fragment pointers: per-ks stride 512 f16; kp1 = next row-block.
    const f16* kp0 = Kf + ((size_t)(kvbase / 16 + wave * 2) * 32 * 64 + lane) * 8;
    const f16* kp1 = kp0 + 16384;
    // V fragment pointer: wave owns db = wave*8 .. +7.
    const f16* vbase = Vf + (((size_t)(kvbase / 32) * 64 + wave * 8) * 64 + lane) * 8;

    f32x4 S[2][2];
    f16x8 kA[8], kB[8];
    int pbOfs = 0;

    auto LOADK = [&](f16x8* buf, int ks0) {
        #pragma unroll
        for (int j = 0; j < 4; ++j) {
            buf[2 * j]     = *(const f16x8*)(kp0 + (ks0 + j) * 512);
            buf[2 * j + 1] = *(const f16x8*)(kp1 + (ks0 + j) * 512);
        }
    };
    auto USEK = [&](const f16x8* kb2, int ks0) {
        #pragma unroll
        for (int j = 0; j < 4; ++j) {
            int ks = ks0 + j;
            f16x8 ah0 = *(const f16x8*)(bh0 + ks * 2048);
            f16x8 ah1 = *(const f16x8*)(bh1 + ks * 2048);
            __builtin_amdgcn_s_setprio(1);
            S[0][0] = mfma16(ah0, kb2[2 * j],     S[0][0]);
            S[0][1] = mfma16(ah0, kb2[2 * j + 1], S[0][1]);
            S[1][0] = mfma16(ah1, kb2[2 * j],     S[1][0]);
            S[1][1] = mfma16(ah1, kb2[2 * j + 1], S[1][1]);
            __builtin_amdgcn_s_setprio(0);
        }
    };
    auto QK = [&]() {
        #pragma unroll
        for (int rg = 0; rg < 2; ++rg)
            #pragma unroll
            for (int cg = 0; cg < 2; ++cg) S[rg][cg] = (f32x4){0.f, 0.f, 0.f, 0.f};
        LOADK(kA, 0);
        LOADK(kB, 4);  USEK(kA, 0);
        LOADK(kA, 8);  USEK(kB, 4);
        LOADK(kB, 12); USEK(kA, 8);
        LOADK(kA, 16); USEK(kB, 12);
        LOADK(kB, 20); USEK(kA, 16);
        LOADK(kA, 24); USEK(kB, 20);
        LOADK(kB, 28); USEK(kA, 24);
                       USEK(kB, 28);
    };

    f32x4 O[2][8];
    #pragma unroll
    for (int rg = 0; rg < 2; ++rg)
        #pragma unroll
        for (int fn = 0; fn < 8; ++fn) O[rg][fn] = (f32x4){0.f, 0.f, 0.f, 0.f};
    float mq[8];
    #pragma unroll
    for (int u = 0; u < 8; ++u) mq[u] = -INFINITY;
    float m2a = -INFINITY, m2b = -INFINITY, l2a = 0.f, l2b = 0.f;

    f16x8 vA[8], vB[8];
    auto LOADV = [&](f16x8* buf, int ks2) {
        #pragma unroll
        for (int fn = 0; fn < 8; ++fn)
            buf[fn] = *(const f16x8*)(vbase + ks2 * 32768 + fn * 512);
    };
    float ba[8], bb[8];
    auto USEV = [&](const f16x8* vb2, int ks2) {
        f16 ba16 = (f16)ba[ks2], bb16 = (f16)bb[ks2];
        f16x8 pa0 = *(const f16x8*)(pr0 + pbOfs + ks2 * 2048);
        f16x8 pa1 = *(const f16x8*)(pr1 + pbOfs + ks2 * 2048);
        #pragma unroll
        for (int j = 0; j < 8; ++j) { pa0[j] *= ba16; pa1[j] *= bb16; }
        __builtin_amdgcn_s_setprio(1);
        #pragma unroll
        for (int fn = 0; fn < 8; ++fn) {
            O[0][fn] = mfma16(pa0, vb2[fn], O[0][fn]);
            O[1][fn] = mfma16(pa1, vb2[fn], O[1][fn]);
        }
        __builtin_amdgcn_s_setprio(0);
    };

    QK();   // tile 0
    int pb = 0;

    for (int it = 0; it < ITERS; ++it) {
        // ---- strip softmax: max, exp, sum over own 32 cols; publish P + {m,s} ----
        #pragma unroll
        for (int rg = 0; rg < 2; ++rg)
            #pragma unroll
            for (int i = 0; i < 4; ++i) {
                float a = S[rg][0][i], b = S[rg][1][i];
                float mx = fmaxf(a, b);
                mx = fmaxf(mx, __shfl_xor(mx, 1));
                mx = fmaxf(mx, __shfl_xor(mx, 2));
                mx = fmaxf(mx, __shfl_xor(mx, 4));
                mx = fmaxf(mx, __shfl_xor(mx, 8));
                float p0 = __expf(a - mx), p1 = __expf(b - mx);
                float s = p0 + p1;
                s += __shfl_xor(s, 1);
                s += __shfl_xor(s, 2);
                s += __shfl_xor(s, 4);
                s += __shfl_xor(s, 8);
                int m = rg * 16 + lg * 4 + i;
                int off0 = pb * 16384 + wave * 2048 + m * 64
                         + ((l15 >> 3) << 4) + ((l15 & 7) << 1);
                *(f16*)((char*)&Pl[0][0] + off0)      = (f16)p0;
                *(f16*)((char*)&Pl[0][0] + off0 + 32) = (f16)p1;
                if (l15 == 0) red[pb][m][wave] = make_float2(mx, s);
            }
        __syncthreads();        // the ONLY barrier in the loop

        pbOfs = pb * 16384;

        // ---- V prefetch: combine-VALU below covers the latency ----
        LOADV(vA, 0);
        LOADV(vB, 1);

        // ---- combine: global row max, beta per strip, l update ----
        float m2a0 = m2a, m2b0 = m2b;
        float M2an = m2a, M2bn = m2b;
        #pragma unroll
        for (int s2 = 0; s2 < 8; ++s2) {
            M2an = fmaxf(M2an, red[pb][l15][s2].x);
            M2bn = fmaxf(M2bn, red[pb][l15 + 16][s2].x);
        }
        float laa = 0.f, lbb = 0.f;
        #pragma unroll
        for (int s2 = 0; s2 < 8; ++s2) {
            float2 ra = red[pb][l15][s2], rb = red[pb][l15 + 16][s2];
            ba[s2] = __expf(ra.x - M2an); laa += ra.y * ba[s2];
            bb[s2] = __expf(rb.x - M2bn); lbb += rb.y * bb[s2];
        }
        l2a = l2a * __expf(m2a - M2an) + laa; m2a = M2an;
        l2b = l2b * __expf(m2b - M2bn) + lbb; m2b = M2bn;

        // ---- defer-max: only rescale O when some row max actually rose ----
        if (__any((M2an > m2a0) || (M2bn > m2b0))) {
            float al[2][4];
            #pragma unroll
            for (int rg = 0; rg < 2; ++rg)
                #pragma unroll
                for (int i = 0; i < 4; ++i) {
                    int u = rg * 4 + i;
                    int src = (lane & 48) | (lg * 4 + i);
                    float Mq = __shfl(rg ? M2bn : M2an, src);
                    al[rg][i] = __expf(mq[u] - Mq);
                    mq[u] = Mq;
                }
            #pragma unroll
            for (int rg = 0; rg < 2; ++rg)
                #pragma unroll
                for (int fn = 0; fn < 8; ++fn)
                    #pragma unroll
                    for (int i = 0; i < 4; ++i)
                        O[rg][fn][i] *= al[rg][i];
        }

        // ---- PV with double-buffered V registers ----
        USEV(vA, 0);  LOADV(vA, 2);
        USEV(vB, 1);  LOADV(vB, 3);
        USEV(vA, 2);  LOADV(vA, 4);
        USEV(vB, 3);  LOADV(vB, 5);
        USEV(vA, 4);  LOADV(vA, 6);
        USEV(vB, 5);  LOADV(vB, 7);
        USEV(vA, 6);
        USEV(vB, 7);

        // ---- advance; next tile's QK; flip P buffer (no closing barrier) ----
        kp0 += (size_t)16 * 16384;
        kp1 += (size_t)16 * 16384;
        vbase += (size_t)8 * 32768;
        if (it + 1 < ITERS) QK();
        pb ^= 1;
    }

    // ---- epilogue: unnormalized O + per-row m/l partials ----
    float* Op = Opart + (size_t)chunk * B_ * D_;
    #pragma unroll
    for (int rg = 0; rg < 2; ++rg)
        #pragma unroll
        for (int fn = 0; fn < 8; ++fn)
            #pragma unroll
            for (int i = 0; i < 4; ++i) {
                int row = b0 + rg * 16 + lg * 4 + i;
                int col = wave * DSLICE + fn * 16 + l15;
                Op[(size_t)row * D_ + col] = O[rg][fn][i];
            }
    if (wave == 0 && lg == 0) {
        Mpart[(size_t)chunk * B_ + b0 + l15]      = m2a;
        Lpart[(size_t)chunk * B_ + b0 + l15]      = l2a;
        Mpart[(size_t)chunk * B_ + b0 + 16 + l15] = m2b;
        Lpart[(size_t)chunk * B_ + b0 + 16 + l15] = l2b;
    }
}

// ---- combine NSPLIT=2 partials -------------------------------------------------
__global__ void combine_k(const float* __restrict__ Opart,
                          const float* __restrict__ Mp, const float* __restrict__ Lp,
                          float* __restrict__ Outg)
{
    int b = blockIdx.x;
    float m0 = Mp[b], m1 = Mp[B_ + b];
    float l0 = Lp[b], l1 = Lp[B_ + b];
    float M  = fmaxf(m0, m1);
    float w0 = __expf(m0 - M), w1 = __expf(m1 - M);
    float inv = 1.f / (w0 * l0 + w1 * l1);
    const float4* O0 = (const float4*)(Opart + (size_t)b * D_);
    const float4* O1 = (const float4*)(Opart + (size_t)B_ * D_ + (size_t)b * D_);
    float4* o = (float4*)(Outg + (size_t)b * D_);
    for (int i = threadIdx.x; i < D_ / 4; i += blockDim.x) {
        float4 a = O0[i], c = O1[i];
        float4 r;
        r.x = (w0 * a.x + w1 * c.x) * inv;
        r.y = (w0 * a.y + w1 * c.y) * inv;
        r.z = (w0 * a.z + w1 * c.z) * inv;
        r.w = (w0 * a.w + w1 * c.w) * inv;
        o[i] = r;
    }
}

extern "C" void kernel_launch(void* const* d_in, const int* in_sizes, int n_in,
                              void* d_out, int out_size, void* d_ws, size_t ws_size,
                              hipStream_t stream) {
    const float* X = (const float*)d_in[0];
    const float* K = (const float*)d_in[1];
    const float* V = (const float*)d_in[2];
    float* Out = (float*)d_out;

    const size_t szKf = (size_t)N_ * D_ * sizeof(f16);   // 64 MiB
    const size_t szVf = (size_t)N_ * D_ * sizeof(f16);   // 64 MiB
    const size_t szOp = 2ull * B_ * D_ * sizeof(float);  // 32 MiB
    const size_t szM  = 2ull * B_ * sizeof(float);

    f16*   Kf = (f16*)d_ws;
    f16*   Vf = (f16*)((char*)d_ws + szKf);
    float* Op = (float*)((char*)d_ws + szKf + szVf);
    float* Mp = (float*)((char*)Op + szOp);
    float* Lp = (float*)((char*)Mp + szM);

    conv_kf<<<(N_ * D_ / 8) / 256, 256, 0, stream>>>(K, Kf);
    conv_vf<<<(N_ * D_ / 8) / 256, 256, 0, stream>>>(V, Vf);
    attn_main<<<256, THREADS, 0, stream>>>(X, Kf, Vf, Op, Mp, Lp);
    combine_k<<<B_, 256, 0, stream>>>(Op, Mp, Lp, Out);
}